// Round 10
// baseline (867.505 us; speedup 1.0000x reference)
//
#include <hip/hip_runtime.h>
#include <hip/hip_bf16.h>

// Problem constants
#define BN_B 64
#define NC 5
#define NH 50
#define NL 32
#define DD 300
#define QQ 200
#define NVOC 50000
#define NGAT 55          // 5 candidate + 50 clicked news GATs
#define NROW 2048        // rows per news GAT (B*L)
#define NUSR 3200        // rows user GAT (B*H)
#define CW 304           // prefix array row width (300 data + col300 = denominator)
#define NT_NEWS 128      // 2048/16
#define NB_NEWS 128      // max bucket index = NROW/16
#define GSTR 320         // padded g row stride (10 K-tiles of 32 for MFMA)
#define NTILES_N 13      // ceil(200/16)
#define KTILES 10        // 320/32
#define BPELT (NTILES_N * KTILES * 64)  // lin_w B-fragment entries (x8 bf16)
#define WNT 19
#define WKT 10
#define WPELT (WNT * WKT * 64)
#define KTBYTES (NTILES_N * 64 * 16)    // bytes per kt lin_w B-tile = 13312
#define KTCHUNK (KTBYTES / 16)          // 832 16-B chunks
#define GCH 1216         // float4 chunks per kt per W matrix (WNT*64)
#define GKCH 2432        // hi+lo chunks per kt
// user direct-P GEMM: K = 3328 = 104 kts, N = 304 = 19 nts
#define PKT 104
#define PNT 19
#define PPELT (PKT * PNT * 64)
#define PSTR 3328
#define PJT 416          // 3328/8 j-groups per row

typedef short bf16x8 __attribute__((ext_vector_type(8)));
typedef short bf16x4 __attribute__((ext_vector_type(4)));
typedef float f32x4 __attribute__((ext_vector_type(4)));

static __device__ __forceinline__ float bf2f(short s) {
  return __uint_as_float(((unsigned)(unsigned short)s) << 16);
}

// ---------------------------------------------------------------------------
// Pack W [300,300] fp32 -> split bf16 (hi/lo) B-fragments. y = 0 news, 1 user.
// kt-major: entry e = (kt*WNT + nt)*64 + lane  (per-kt tile contiguous).
// ---------------------------------------------------------------------------
__global__ __launch_bounds__(256) void k_packW(const float* __restrict__ W0,
                                               const float* __restrict__ W1,
                                               __hip_bfloat16* __restrict__ h0,
                                               __hip_bfloat16* __restrict__ l0,
                                               __hip_bfloat16* __restrict__ h1,
                                               __hip_bfloat16* __restrict__ l1) {
  const float* Wm = blockIdx.y ? W1 : W0;
  __hip_bfloat16* Bhi = blockIdx.y ? h1 : h0;
  __hip_bfloat16* Blo = blockIdx.y ? l1 : l0;
  int e = blockIdx.x * 256 + threadIdx.x;
  if (e >= WPELT) return;
  int lane = e & 63, nt = (e >> 6) % WNT, kt = (e >> 6) / WNT;
  int n = nt * 16 + (lane & 15);
  int k0 = kt * 32 + (lane >> 4) * 8;
  __hip_bfloat16 hv[8], lv[8];
#pragma unroll
  for (int j = 0; j < 8; ++j) {
    int k = k0 + j;
    float v = (k < DD && n < DD) ? Wm[(size_t)k * DD + n] : 0.f;
    __hip_bfloat16 h = __float2bfloat16(v);
    hv[j] = h;
    lv[j] = __float2bfloat16(v - __bfloat162float(h));
  }
  *(bf16x8*)(Bhi + (size_t)e * 8) = *(const bf16x8*)hv;
  *(bf16x8*)(Blo + (size_t)e * 8) = *(const bf16x8*)lv;
}

// Pack lin_w [Q,300] -> bf16 B-fragments, kt-major. y = 0 news, 1 user.
__global__ __launch_bounds__(256) void k_packB(const float* __restrict__ lw0,
                                               const float* __restrict__ lw1,
                                               __hip_bfloat16* __restrict__ B0,
                                               __hip_bfloat16* __restrict__ B1) {
  const float* lw = blockIdx.y ? lw1 : lw0;
  __hip_bfloat16* Bp = blockIdx.y ? B1 : B0;
  int e = blockIdx.x * 256 + threadIdx.x;
  if (e >= BPELT) return;
  int lane = e & 63, nt = (e >> 6) % NTILES_N, kt = (e >> 6) / NTILES_N;
  int n = nt * 16 + (lane & 15);
  int k0 = kt * 32 + (lane >> 4) * 8;
  __hip_bfloat16 vals[8];
#pragma unroll
  for (int j = 0; j < 8; ++j) {
    int k = k0 + j;
    float v = (n < QQ && k < DD) ? lw[(size_t)n * DD + k] : 0.f;
    vals[j] = __float2bfloat16(v);
  }
  *(bf16x8*)(Bp + (size_t)e * 8) = *(const bf16x8*)vals;
}

// ---------------------------------------------------------------------------
// C[M,300] = A[M,300] @ W[300,300] via split-bf16 MFMA, LDS-STAGED B.
// Block = 512 threads (8 waves) = 128 rows. Per-kt hi+lo tile (38.9 KB)
// double-buffered in LDS via register prefetch. Fused s1/s2 epilogue.
// ---------------------------------------------------------------------------
__global__ __launch_bounds__(512) void k_gemm_mfma(const float* __restrict__ A,
                                                   const __hip_bfloat16* __restrict__ Bhi,
                                                   const __hip_bfloat16* __restrict__ Blo,
                                                   const float* __restrict__ avec,
                                                   float* __restrict__ C,
                                                   float* __restrict__ s1o,
                                                   float* __restrict__ s2o, int M) {
  __shared__ __align__(16) float4 Bs4[2][GKCH];
  const int tid = threadIdx.x;
  const int wave = tid >> 6, lane = tid & 63;
  const int quad = lane >> 4, l16 = lane & 15;
  const int rowA = blockIdx.x * 128 + wave * 16 + l16;
  const float* ar = A + (size_t)rowA * DD;
  const float4* hsrc = (const float4*)Bhi;
  const float4* lsrc = (const float4*)Blo;
  float4 st[5];

#define LOADKT(kt)                                                         \
  {                                                                        \
    _Pragma("unroll") for (int s = 0; s < 5; ++s) {                        \
      int idx = s * 512 + tid;                                             \
      if (idx < GKCH)                                                      \
        st[s] = (idx < GCH) ? hsrc[(size_t)(kt)*GCH + idx]                 \
                            : lsrc[(size_t)(kt)*GCH + idx - GCH];          \
    }                                                                      \
  }
#define STOREBUF(b)                                                        \
  {                                                                        \
    _Pragma("unroll") for (int s = 0; s < 5; ++s) {                        \
      int idx = s * 512 + tid;                                             \
      if (idx < GKCH) Bs4[b][idx] = st[s];                                 \
    }                                                                      \
  }

  LOADKT(0); STOREBUF(0); LOADKT(1);
  __syncthreads();

  f32x4 acc[WNT];
#pragma unroll
  for (int nt = 0; nt < WNT; ++nt) acc[nt] = (f32x4){0.f, 0.f, 0.f, 0.f};
  int c = 0;
  for (int kt = 0; kt < WKT; ++kt) {
    const int k0 = kt * 32 + quad * 8;
    float av[8];
    if (rowA < M && k0 + 8 <= DD) {
      float4 v0 = *(const float4*)(ar + k0);
      float4 v1 = *(const float4*)(ar + k0 + 4);
      av[0] = v0.x; av[1] = v0.y; av[2] = v0.z; av[3] = v0.w;
      av[4] = v1.x; av[5] = v1.y; av[6] = v1.z; av[7] = v1.w;
    } else {
#pragma unroll
      for (int j = 0; j < 8; ++j) {
        int k = k0 + j;
        av[j] = (rowA < M && k < DD) ? ar[k] : 0.f;
      }
    }
    __hip_bfloat16 hv[8], lv[8];
#pragma unroll
    for (int j = 0; j < 8; ++j) {
      __hip_bfloat16 h = __float2bfloat16(av[j]);
      hv[j] = h;
      lv[j] = __float2bfloat16(av[j] - __bfloat162float(h));
    }
    const bf16x8 ah = *(const bf16x8*)hv;
    const bf16x8 al = *(const bf16x8*)lv;
    const bf16x8* bh = (const bf16x8*)&Bs4[c][0] + lane;
    const bf16x8* bl = (const bf16x8*)&Bs4[c][GCH] + lane;
#pragma unroll
    for (int nt = 0; nt < WNT; ++nt) {
      bf16x8 bhf = bh[nt * 64], blf = bl[nt * 64];
      acc[nt] = __builtin_amdgcn_mfma_f32_16x16x32_bf16(ah, bhf, acc[nt], 0, 0, 0);
      acc[nt] = __builtin_amdgcn_mfma_f32_16x16x32_bf16(al, bhf, acc[nt], 0, 0, 0);
      acc[nt] = __builtin_amdgcn_mfma_f32_16x16x32_bf16(ah, blf, acc[nt], 0, 0, 0);
    }
    if (kt < WKT - 1) {
      __syncthreads();
      STOREBUF(c ^ 1);
      if (kt < WKT - 2) LOADKT(kt + 2);
      __syncthreads();
      c ^= 1;
    }
  }
  const int mbase = blockIdx.x * 128 + wave * 16 + quad * 4;
#pragma unroll
  for (int nt = 0; nt < WNT; ++nt) {
    int n = nt * 16 + l16;
    if (n < DD) {
#pragma unroll
      for (int r = 0; r < 4; ++r) {
        int mr = mbase + r;
        if (mr < M) C[(size_t)mr * DD + n] = acc[nt][r];
      }
    }
  }
  // s1/s2 epilogue
  float a1v[WNT], a2v[WNT];
#pragma unroll
  for (int nt = 0; nt < WNT; ++nt) {
    int n = nt * 16 + l16;
    a1v[nt] = (n < DD) ? avec[n] : 0.f;
    a2v[nt] = (n < DD) ? avec[DD + n] : 0.f;
  }
#pragma unroll
  for (int r = 0; r < 4; ++r) {
    float p1 = 0.f, p2 = 0.f;
#pragma unroll
    for (int nt = 0; nt < WNT; ++nt) {
      p1 = fmaf(acc[nt][r], a1v[nt], p1);
      p2 = fmaf(acc[nt][r], a2v[nt], p2);
    }
    p1 += __shfl_xor(p1, 1, 64); p1 += __shfl_xor(p1, 2, 64);
    p1 += __shfl_xor(p1, 4, 64); p1 += __shfl_xor(p1, 8, 64);
    p2 += __shfl_xor(p2, 1, 64); p2 += __shfl_xor(p2, 2, 64);
    p2 += __shfl_xor(p2, 4, 64); p2 += __shfl_xor(p2, 8, 64);
    int mr = mbase + r;
    if (l16 == 0 && mr < M) { s1o[mr] = p1; s2o[mr] = p2; }
  }
#undef LOADKT
#undef STOREBUF
}

// ---------------------------------------------------------------------------
// Bitonic sort of s2 + exp tables + rank/bucket epilogue (news GATs).
// ---------------------------------------------------------------------------
__global__ __launch_bounds__(1024) void k_sort2(const int* __restrict__ cand,
                                                const int* __restrict__ clicked,
                                                const float* __restrict__ s2src,
                                                const float* __restrict__ s1src,
                                                int* __restrict__ perm,
                                                float* __restrict__ E1, float* __restrict__ E02,
                                                int* __restrict__ rlist, float* __restrict__ rs1,
                                                int* __restrict__ boff,
                                                int N, int NB) {
  __shared__ float sval[2048];
  __shared__ int spay[2048];
  __shared__ int cnt[224];
  __shared__ int ofs[224];
  const int m = blockIdx.x;
  const int tid = threadIdx.x;
  int* perm_g = perm + (size_t)m * N;
  float* E1_g = E1 + (size_t)m * N;
  float* E02_g = E02 + (size_t)m * N;

  for (int i = tid; i < N; i += 1024) {
    int b = i >> 5, l = i & 31;
    int tok = (m < NC) ? cand[b * (NC * NL) + m * NL + l]
                       : clicked[b * (NH * NL) + (m - NC) * NL + l];
    sval[i] = s2src[tok]; spay[i] = tok;
  }
  __syncthreads();
  for (int k = 2; k <= N; k <<= 1) {
    for (int j = k >> 1; j > 0; j >>= 1) {
      for (int i = tid; i < N; i += 1024) {
        int ixj = i ^ j;
        if (ixj > i) {
          bool asc = ((i & k) == 0);
          float a = sval[i], bb = sval[ixj];
          bool sw = asc ? (a > bb) : (a < bb);
          if (sw) {
            sval[i] = bb; sval[ixj] = a;
            int t = spay[i]; spay[i] = spay[ixj]; spay[ixj] = t;
          }
        }
      }
      __syncthreads();
    }
  }
  for (int i = tid; i < N; i += 1024) {
    E1_g[i] = expf(sval[i]);
    E02_g[i] = expf(0.2f * sval[i]);
    perm_g[i] = spay[i];
  }
  __syncthreads();
  for (int t = tid; t <= NB; t += 1024) cnt[t] = 0;
  __syncthreads();
  int* kil = spay;  // reuse (perm already written)
  for (int r = tid; r < N; r += 1024) {
    int b = r >> 5, l = r & 31;
    int tok = (m < NC) ? cand[b * (NC * NL) + m * NL + l]
                       : clicked[b * (NH * NL) + (m - NC) * NL + l];
    float tau = -s1src[tok];
    int lo = 0, hi = N;
    while (lo < hi) { int mid = (lo + hi) >> 1; if (sval[mid] <= tau) lo = mid + 1; else hi = mid; }
    kil[r] = lo;
    atomicAdd(&cnt[lo >> 4], 1);
  }
  __syncthreads();
  if (tid == 0) {
    int run = 0;
    for (int t = 0; t <= NB; ++t) { ofs[t] = run; run += cnt[t]; cnt[t] = ofs[t]; }
  }
  __syncthreads();
  int* rlist_g = rlist + (size_t)m * N;
  float* rs1_g = rs1 + (size_t)m * N;
  for (int r = tid; r < N; r += 1024) {
    int ki = kil[r];
    int pos = atomicAdd(&cnt[ki >> 4], 1);
    rlist_g[pos] = (ki << 16) | r;
    int b = r >> 5, l = r & 31;
    int tok = (m < NC) ? cand[b * (NC * NL) + m * NL + l]
                       : clicked[b * (NH * NL) + (m - NC) * NL + l];
    rs1_g[pos] = s1src[tok];
  }
  int* boff_g = boff + (size_t)m * (NB + 2);
  for (int t = tid; t <= NB; t += 1024) boff_g[t] = ofs[t];
  if (tid == 0) boff_g[NB + 1] = N;
}

// ---------------------------------------------------------------------------
// Chunked weighted prefix accumulation (local prefixes) + chunk totals T.
// ---------------------------------------------------------------------------
__global__ __launch_bounds__(320) void k_scan(const float* __restrict__ base,
                                              const int* __restrict__ perm,
                                              const float* __restrict__ E1,
                                              const float* __restrict__ E02,
                                              float* __restrict__ C1, float* __restrict__ C02,
                                              float* __restrict__ T1, float* __restrict__ T02,
                                              int Epad, int cstride, int nkc) {
  const int g = blockIdx.y, kc = blockIdx.x;
  const int col = threadIdx.x;
  const int* perm_g = perm + (size_t)g * Epad;
  const float* E1_g = E1 + (size_t)g * Epad;
  const float* E02_g = E02 + (size_t)g * Epad;
  float* C1_g = C1 + (size_t)g * cstride * CW;
  float* C02_g = C02 + (size_t)g * cstride * CW;
  const bool datacol = (col < DD);
  const float wden = (col == DD) ? 1.f : 0.f;
  float acc1 = 0.f, acc2 = 0.f;
  const int k0 = kc * 256;
#pragma unroll 8
  for (int kk = 0; kk < 256; ++kk) {
    int k = k0 + kk;
    int tok = perm_g[k];
    float e1 = E1_g[k], e02 = E02_g[k];
    float w = datacol ? base[(size_t)tok * DD + col] : wden;
    acc1 = fmaf(e1, w, acc1);
    acc2 = fmaf(e02, w, acc2);
    if ((kk & 15) == 15) {
      int t = (k + 1) >> 4;
      if (col < CW) { C1_g[(size_t)t * CW + col] = acc1; C02_g[(size_t)t * CW + col] = acc2; }
    }
  }
  if (col < CW) {
    T1[((size_t)g * nkc + kc) * CW + col] = acc1;
    T02[((size_t)g * nkc + kc) * CW + col] = acc2;
  }
}

// ---------------------------------------------------------------------------
// Bucketed GAT row construction with inline prefix fix-up (news path).
// ---------------------------------------------------------------------------
__global__ __launch_bounds__(320) void k_rows2(
    const float* __restrict__ base,
    const int* __restrict__ perm, const float* __restrict__ E1, const float* __restrict__ E02,
    const float* __restrict__ C1, const float* __restrict__ C02,
    const float* __restrict__ T1, const float* __restrict__ T02,
    const int* __restrict__ rlist, const float* __restrict__ rs1,
    const int* __restrict__ boff,
    __hip_bfloat16* __restrict__ gout,
    int N, int NT, int Epad, int NB, int nkc) {
  __shared__ float U1[16][CW];
  __shared__ float U02[16][CW];
  __shared__ int tokL[16];
  __shared__ float e1L[16], e02L[16];
  const int t = blockIdx.x, g = blockIdx.y;
  const int col = threadIdx.x;
  const int* boff_g = boff + (size_t)g * (NB + 2);
  const int i0 = boff_g[t], i1 = boff_g[t + 1];
  if (i0 >= i1) return;
  const int* perm_g = perm + (size_t)g * Epad;
  const float* E1_g = E1 + (size_t)g * Epad;
  const float* E02_g = E02 + (size_t)g * Epad;
  if (col < 16) {
    int idx = t * 16 + col;
    bool v = idx < N;
    tokL[col] = v ? perm_g[idx] : 0;
    e1L[col] = v ? E1_g[idx] : 0.f;
    e02L[col] = v ? E02_g[idx] : 0.f;
  }
  __syncthreads();
  if (col < CW) {
    const int kc = (t == 0) ? 0 : ((t - 1) >> 4);
    float tot1 = 0.f, pre1 = 0.f, pre02 = 0.f;
#pragma unroll
    for (int c = 0; c < 13; ++c) {
      if (c < nkc) {
        float tv = T1[((size_t)g * nkc + c) * CW + col];
        tot1 += tv;
        if (c < kc) {
          pre1 += tv;
          pre02 += T02[((size_t)g * nkc + c) * CW + col];
        }
      }
    }
    if (t > 0) {
      pre1 += C1[((size_t)g * (NT + 1) + t) * CW + col];
      pre02 += C02[((size_t)g * (NT + 1) + t) * CW + col];
    }
    float u1 = tot1 - pre1;
    float u02 = pre02;
    float wv[16];
#pragma unroll
    for (int j = 0; j < 16; ++j) {
      if (col < DD) wv[j] = ((t * 16 + j) < N) ? base[(size_t)tokL[j] * DD + col] : 0.f;
      else wv[j] = (col == DD) ? 1.f : 0.f;
    }
#pragma unroll
    for (int j = 0; j < 16; ++j) {
      U1[j][col] = u1; U02[j][col] = u02;
      u1 = fmaf(-e1L[j], wv[j], u1);
      u02 = fmaf(e02L[j], wv[j], u02);
    }
  }
  __syncthreads();
  const int wave = col >> 6, lane = col & 63;
  const int* rlist_g = rlist + (size_t)g * N;
  const float* rs1_g = rs1 + (size_t)g * N;
  for (int i = i0 + wave; i < i1; i += 5) {
    int e = rlist_g[i];
    int r = e & 0xffff, nr = (e >> 16) & 15;
    float s1 = rs1_g[i];
    float es1 = __expf(s1), es02 = __expf(0.2f * s1);
    float den = es1 * U1[nr][DD] + es02 * U02[nr][DD];
    float rden = 1.f / den;
    __hip_bfloat16* gr = gout + ((size_t)g * N + r) * GSTR;
#pragma unroll
    for (int cc = 0; cc < 2; ++cc) {
      int ch = lane + 64 * cc;               // 16-B column chunk index
      if (ch < 80) {
        short ov[4];
        if (ch < 75) {                        // cols 0..299
          const int c0 = ch * 4;
          float4 u1v = *(const float4*)&U1[nr][c0];
          float4 u2v = *(const float4*)&U02[nr][c0];
          float n0 = fmaf(es1, u1v.x, es02 * u2v.x) * rden;
          float n1 = fmaf(es1, u1v.y, es02 * u2v.y) * rden;
          float n2 = fmaf(es1, u1v.z, es02 * u2v.z) * rden;
          float n3 = fmaf(es1, u1v.w, es02 * u2v.w) * rden;
          float g0 = (n0 > 0.f) ? n0 : (__expf(n0) - 1.f);
          float g1 = (n1 > 0.f) ? n1 : (__expf(n1) - 1.f);
          float g2 = (n2 > 0.f) ? n2 : (__expf(n2) - 1.f);
          float g3 = (n3 > 0.f) ? n3 : (__expf(n3) - 1.f);
          __hip_bfloat16 h0 = __float2bfloat16(g0), h1 = __float2bfloat16(g1);
          __hip_bfloat16 h2 = __float2bfloat16(g2), h3 = __float2bfloat16(g3);
          ov[0] = *(short*)&h0; ov[1] = *(short*)&h1;
          ov[2] = *(short*)&h2; ov[3] = *(short*)&h3;
        } else {                              // cols 300..319 zero pad
          ov[0] = ov[1] = ov[2] = ov[3] = 0;
        }
        *(bf16x4*)(gr + ch * 4) = *(bf16x4*)ov;
      }
    }
  }
}

// ---------------------------------------------------------------------------
// Fused news logits + additive attention, LDS-staged B. 512 thr = 128 rows.
// ---------------------------------------------------------------------------
__global__ __launch_bounds__(512) void k_logits_attn(
    const __hip_bfloat16* __restrict__ g, const __hip_bfloat16* __restrict__ Bp,
    const float* __restrict__ lin_b, const float* __restrict__ query,
    float* __restrict__ cand_enc, float* __restrict__ clicked_enc) {
  __shared__ __align__(16) short Bs[2][NTILES_N * 512];  // 2 x 13312 B
  __shared__ float lg[128];
  __shared__ float wgt[128];
  __shared__ float accw[8][GSTR];
  const int tid = threadIdx.x;
  const int wave = tid >> 6, lane = tid & 63;
  const int quad = lane >> 4, l16 = lane & 15;
  const int m = blockIdx.x >> 4;             // 16 blocks per gat
  const int rbase = (blockIdx.x & 15) * 128; // row within gat
  const __hip_bfloat16* grow =
      g + ((size_t)m * NROW + rbase + wave * 16 + l16) * GSTR + quad * 8;
  bf16x8 afr[KTILES];
#pragma unroll
  for (int kt = 0; kt < KTILES; ++kt) afr[kt] = *(const bf16x8*)(grow + kt * 32);

  const float4* bsrc = (const float4*)Bp;
  float4* bdst0 = (float4*)&Bs[0][0];
  float4* bdst1 = (float4*)&Bs[1][0];
  float4 st0, st1;
  {
    st0 = bsrc[tid];
    if (tid < KTCHUNK - 512) st1 = bsrc[512 + tid];
    bdst0[tid] = st0;
    if (tid < KTCHUNK - 512) bdst0[512 + tid] = st1;
    st0 = bsrc[KTCHUNK + tid];
    if (tid < KTCHUNK - 512) st1 = bsrc[KTCHUNK + 512 + tid];
  }
  __syncthreads();
  f32x4 acc[NTILES_N];
#pragma unroll
  for (int nt = 0; nt < NTILES_N; ++nt) acc[nt] = (f32x4){0.f, 0.f, 0.f, 0.f};
  int c = 0;
  for (int kt = 0; kt < KTILES; ++kt) {
    const bf16x8* bp = (const bf16x8*)&Bs[c][0] + lane;
#pragma unroll
    for (int nt = 0; nt < NTILES_N; ++nt)
      acc[nt] = __builtin_amdgcn_mfma_f32_16x16x32_bf16(afr[kt], bp[nt * 64], acc[nt], 0, 0, 0);
    if (kt < KTILES - 1) {
      __syncthreads();
      float4* bd = c ? bdst0 : bdst1;
      bd[tid] = st0;
      if (tid < KTCHUNK - 512) bd[512 + tid] = st1;
      if (kt < KTILES - 2) {
        st0 = bsrc[(size_t)(kt + 2) * KTCHUNK + tid];
        if (tid < KTCHUNK - 512) st1 = bsrc[(size_t)(kt + 2) * KTCHUNK + 512 + tid];
      }
      __syncthreads();
      c ^= 1;
    }
  }
  float part[4] = {0.f, 0.f, 0.f, 0.f};
#pragma unroll
  for (int nt = 0; nt < NTILES_N; ++nt) {
    const int n = nt * 16 + l16;
    const float qv = (n < QQ) ? query[n] : 0.f;
    const float bv = (n < QQ) ? lin_b[n] : 0.f;
#pragma unroll
    for (int r = 0; r < 4; ++r)
      part[r] = fmaf(tanhf(acc[nt][r] + bv), qv, part[r]);
  }
#pragma unroll
  for (int r = 0; r < 4; ++r) {
    float p = part[r];
    p += __shfl_xor(p, 1, 64); p += __shfl_xor(p, 2, 64);
    p += __shfl_xor(p, 4, 64); p += __shfl_xor(p, 8, 64);
    if (l16 == 0) lg[wave * 16 + quad * 4 + r] = p;
  }
  __syncthreads();
  if (tid < 128) {
    float v = lg[tid];
    float mx = v;
    mx = fmaxf(mx, __shfl_xor(mx, 1, 64)); mx = fmaxf(mx, __shfl_xor(mx, 2, 64));
    mx = fmaxf(mx, __shfl_xor(mx, 4, 64)); mx = fmaxf(mx, __shfl_xor(mx, 8, 64));
    mx = fmaxf(mx, __shfl_xor(mx, 16, 64));
    float e = expf(v - mx), sm = e;
    sm += __shfl_xor(sm, 1, 64); sm += __shfl_xor(sm, 2, 64);
    sm += __shfl_xor(sm, 4, 64); sm += __shfl_xor(sm, 8, 64);
    sm += __shfl_xor(sm, 16, 64);
    wgt[tid] = e / sm;
  }
  __syncthreads();
  const float w = wgt[wave * 16 + l16];
#pragma unroll
  for (int kt = 0; kt < KTILES; ++kt) {
#pragma unroll
    for (int j = 0; j < 8; ++j) {
      float v = bf2f(afr[kt][j]) * w;
      v += __shfl_xor(v, 1, 64); v += __shfl_xor(v, 2, 64);
      v += __shfl_xor(v, 4, 64); v += __shfl_xor(v, 8, 64);
      if (l16 == 0) accw[wave][kt * 32 + quad * 8 + j] = v;
    }
  }
  __syncthreads();
  const int b0 = rbase >> 5;
  for (int idx = tid; idx < 4 * DD; idx += 512) {
    int j = idx / DD, cc = idx % DD;
    float* op = (m < NC) ? (cand_enc + ((size_t)(b0 + j) * NC + m) * DD)
                         : (clicked_enc + ((size_t)(b0 + j) * NH + (m - NC)) * DD);
    op[cc] = accw[2 * j][cc] + accw[2 * j + 1][cc];
  }
}

// ---------------------------------------------------------------------------
// USER PATH (direct rank-1 attention, no sort):
// P[i,j] = exp(leaky(s1_i + s2_j)) in bf16; g_user = elu((P@Wh_aug)/den).
// ---------------------------------------------------------------------------
// Build P [NUSR x PSTR] bf16. One thread = 8 consecutive j of one row i.
__global__ __launch_bounds__(256) void k_pbuild(const float* __restrict__ s1u,
                                                const float* __restrict__ s2u,
                                                __hip_bfloat16* __restrict__ P) {
  int gid = blockIdx.x * 256 + threadIdx.x;
  if (gid >= NUSR * PJT) return;
  int i = gid / PJT, jg = gid % PJT;
  int j0 = jg * 8;
  float s1 = s1u[i];
  __hip_bfloat16 ov[8];
#pragma unroll
  for (int q = 0; q < 8; ++q) {
    int j = j0 + q;
    float w = 0.f;
    if (j < NUSR) {
      float s = s1 + s2u[j];
      w = __expf(s > 0.f ? s : 0.2f * s);
    }
    ov[q] = __float2bfloat16(w);
  }
  *(bf16x8*)(P + (size_t)i * PSTR + j0) = *(const bf16x8*)ov;
}

// Pack Wh_aug [K=3328 x N=304] -> bf16 B-fragments, kt-major. col 300 = ones.
__global__ __launch_bounds__(256) void k_packP(const float* __restrict__ Wh,
                                               __hip_bfloat16* __restrict__ Bp) {
  int e = blockIdx.x * 256 + threadIdx.x;
  if (e >= PPELT) return;
  int lane = e & 63, nt = (e >> 6) % PNT, kt = (e >> 6) / PNT;
  int n = nt * 16 + (lane & 15);
  int k0 = kt * 32 + (lane >> 4) * 8;
  __hip_bfloat16 vals[8];
#pragma unroll
  for (int j = 0; j < 8; ++j) {
    int k = k0 + j;
    float v = 0.f;
    if (k < NUSR) {
      if (n < DD) v = Wh[(size_t)k * DD + n];
      else if (n == DD) v = 1.f;
    }
    vals[j] = __float2bfloat16(v);
  }
  *(bf16x8*)(Bp + (size_t)e * 8) = *(const bf16x8*)vals;
}

// g_user = elu((P @ Wh_aug)/den) with den = output col 300.
// Block = 256 thr (4 waves, 64 rows), grid = 50. B staged per-kt in LDS
// (19.5 KB, double-buffered, register prefetch).
__global__ __launch_bounds__(256) void k_pgemm(const __hip_bfloat16* __restrict__ P,
                                               const __hip_bfloat16* __restrict__ Bp,
                                               __hip_bfloat16* __restrict__ gout) {
  __shared__ __align__(16) float4 Bs4[2][PNT * 64];  // 2 x 19456 B
  const int tid = threadIdx.x;
  const int wave = tid >> 6, lane = tid & 63;
  const int quad = lane >> 4, l16 = lane & 15;
  const int rowA = blockIdx.x * 64 + wave * 16 + l16;
  const __hip_bfloat16* ar = P + (size_t)rowA * PSTR;
  const float4* bsrc = (const float4*)Bp;
  const int NCH = PNT * 64;  // 1216 float4 chunks per kt
  float4 st[5];

#define PLOADKT(kt)                                                        \
  {                                                                        \
    _Pragma("unroll") for (int s = 0; s < 5; ++s) {                        \
      int idx = s * 256 + tid;                                             \
      if (idx < NCH) st[s] = bsrc[(size_t)(kt)*NCH + idx];                 \
    }                                                                      \
  }
#define PSTOREBUF(b)                                                       \
  {                                                                        \
    _Pragma("unroll") for (int s = 0; s < 5; ++s) {                        \
      int idx = s * 256 + tid;                                             \
      if (idx < NCH) Bs4[b][idx] = st[s];                                  \
    }                                                                      \
  }

  PLOADKT(0); PSTOREBUF(0); PLOADKT(1);
  __syncthreads();
  f32x4 acc[PNT];
#pragma unroll
  for (int nt = 0; nt < PNT; ++nt) acc[nt] = (f32x4){0.f, 0.f, 0.f, 0.f};
  int c = 0;
  for (int kt = 0; kt < PKT; ++kt) {
    bf16x8 a = *(const bf16x8*)(ar + kt * 32 + quad * 8);
    const bf16x8* bp = (const bf16x8*)&Bs4[c][0] + lane;
#pragma unroll
    for (int nt = 0; nt < PNT; ++nt)
      acc[nt] = __builtin_amdgcn_mfma_f32_16x16x32_bf16(a, bp[nt * 64], acc[nt], 0, 0, 0);
    if (kt < PKT - 1) {
      __syncthreads();
      PSTOREBUF(c ^ 1);
      if (kt < PKT - 2) PLOADKT(kt + 2);
      __syncthreads();
      c ^= 1;
    }
  }
  // epilogue: den = col 300 (nt 18, l16 12); normalize, elu, store bf16 rows.
  const int rbase = blockIdx.x * 64 + wave * 16 + quad * 4;
#pragma unroll
  for (int r = 0; r < 4; ++r) {
    float den = __shfl(acc[18][r], (lane & 48) | 12, 64);
    float rden = 1.f / den;
    __hip_bfloat16* gr = gout + (size_t)(rbase + r) * GSTR;
#pragma unroll
    for (int nt = 0; nt < PNT; ++nt) {
      int n = nt * 16 + l16;
      if (n < DD) {
        float v = acc[nt][r] * rden;
        float gg = (v > 0.f) ? v : (__expf(v) - 1.f);
        gr[n] = __float2bfloat16(gg);
      } else {
        gr[n] = __float2bfloat16(0.f);       // cols 300..303
      }
    }
    gr[304 + l16] = __float2bfloat16(0.f);   // cols 304..319
  }
#undef PLOADKT
#undef PSTOREBUF
}

// ---------------------------------------------------------------------------
// Fused user logits + attention + click-score dot. Block = one b (50 rows).
// ---------------------------------------------------------------------------
__global__ __launch_bounds__(256) void k_user_attn(
    const __hip_bfloat16* __restrict__ g, const __hip_bfloat16* __restrict__ Bp,
    const float* __restrict__ lin_b, const float* __restrict__ query,
    const float* __restrict__ cand_enc, float* __restrict__ out) {
  __shared__ float lg[64];
  __shared__ float wgt[64];
  __shared__ float accw[4][GSTR];
  __shared__ float uenc[CW];
  __shared__ float wred[4];
  const int b = blockIdx.x, tid = threadIdx.x;
  const int wave = tid >> 6, lane = tid & 63;
  const int quad = lane >> 4, l16 = lane & 15;
  const int rl = wave * 16 + l16;
  const int rclamp = (rl < NH) ? rl : 0;
  const __hip_bfloat16* grow = g + ((size_t)b * NH + rclamp) * GSTR + quad * 8;
  bf16x8 afr[KTILES];
#pragma unroll
  for (int kt = 0; kt < KTILES; ++kt) afr[kt] = *(const bf16x8*)(grow + kt * 32);
  f32x4 acc[NTILES_N];
#pragma unroll
  for (int nt = 0; nt < NTILES_N; ++nt) acc[nt] = (f32x4){0.f, 0.f, 0.f, 0.f};
  for (int kt = 0; kt < KTILES; ++kt) {
    const bf16x8* bp = (const bf16x8*)Bp + (size_t)kt * NTILES_N * 64 + lane;
#pragma unroll
    for (int nt = 0; nt < NTILES_N; ++nt)
      acc[nt] = __builtin_amdgcn_mfma_f32_16x16x32_bf16(afr[kt], bp[nt * 64], acc[nt], 0, 0, 0);
  }
  float part[4] = {0.f, 0.f, 0.f, 0.f};
#pragma unroll
  for (int nt = 0; nt < NTILES_N; ++nt) {
    const int n = nt * 16 + l16;
    const float qv = (n < QQ) ? query[n] : 0.f;
    const float bv = (n < QQ) ? lin_b[n] : 0.f;
#pragma unroll
    for (int r = 0; r < 4; ++r)
      part[r] = fmaf(tanhf(acc[nt][r] + bv), qv, part[r]);
  }
#pragma unroll
  for (int r = 0; r < 4; ++r) {
    float p = part[r];
    p += __shfl_xor(p, 1, 64); p += __shfl_xor(p, 2, 64);
    p += __shfl_xor(p, 4, 64); p += __shfl_xor(p, 8, 64);
    if (l16 == 0) lg[wave * 16 + quad * 4 + r] = p;
  }
  __syncthreads();
  if (tid < 64) {
    float v = (tid < NH) ? lg[tid] : -3.4e38f;
    float mx = v;
    for (int o = 32; o; o >>= 1) mx = fmaxf(mx, __shfl_xor(mx, o, 64));
    float e = (tid < NH) ? expf(v - mx) : 0.f;
    float sm = e;
    for (int o = 32; o; o >>= 1) sm += __shfl_xor(sm, o, 64);
    wgt[tid] = (tid < NH) ? e / sm : 0.f;
  }
  __syncthreads();
  const float w = (rl < NH) ? wgt[rl] : 0.f;
#pragma unroll
  for (int kt = 0; kt < KTILES; ++kt) {
#pragma unroll
    for (int j = 0; j < 8; ++j) {
      float v = bf2f(afr[kt][j]) * w;
      v += __shfl_xor(v, 1, 64); v += __shfl_xor(v, 2, 64);
      v += __shfl_xor(v, 4, 64); v += __shfl_xor(v, 8, 64);
      if (l16 == 0) accw[wave][kt * 32 + quad * 8 + j] = v;
    }
  }
  __syncthreads();
  for (int c = tid; c < DD; c += 256)
    uenc[c] = accw[0][c] + accw[1][c] + accw[2][c] + accw[3][c];
  __syncthreads();
  for (int c5 = 0; c5 < NC; ++c5) {
    const float* cp = cand_enc + ((size_t)b * NC + c5) * DD;
    float s = 0.f;
    for (int d = tid; d < DD; d += 256) s = fmaf(uenc[d], cp[d], s);
    for (int o = 32; o; o >>= 1) s += __shfl_xor(s, o, 64);
    if (lane == 0) wred[wave] = s;
    __syncthreads();
    if (tid == 0) out[b * NC + c5] = wred[0] + wred[1] + wred[2] + wred[3];
    __syncthreads();
  }
}

// ---------------------------------------------------------------------------
extern "C" void kernel_launch(void* const* d_in, const int* in_sizes, int n_in,
                              void* d_out, int out_size, void* d_ws, size_t ws_size,
                              hipStream_t stream) {
  const int* cand = (const int*)d_in[0];
  const int* clicked = (const int*)d_in[1];
  const float* emb = (const float*)d_in[2];
  const float* news_W = (const float*)d_in[3];
  const float* news_a = (const float*)d_in[4];
  const float* news_lw = (const float*)d_in[5];
  const float* news_lb = (const float*)d_in[6];
  const float* news_q = (const float*)d_in[7];
  const float* user_W = (const float*)d_in[8];
  const float* user_a = (const float*)d_in[9];
  const float* user_lw = (const float*)d_in[10];
  const float* user_lb = (const float*)d_in[11];
  const float* user_q = (const float*)d_in[12];
  float* out = (float*)d_out;

  float* W = (float*)d_ws;
  size_t o = 0;
  auto nxt = [&](size_t n) { size_t c = o; o += (n + 63) & ~(size_t)63; return c; };
  float* EW = W + nxt((size_t)NVOC * DD);
  float* s1v = W + nxt(NVOC);
  float* s2v = W + nxt(NVOC);
  int* perm = (int*)(W + nxt((size_t)NGAT * NROW));
  float* E1 = W + nxt((size_t)NGAT * NROW);
  float* E02 = W + nxt((size_t)NGAT * NROW);
  float* C1 = W + nxt((size_t)NGAT * (NT_NEWS + 1) * CW);
  float* C02 = W + nxt((size_t)NGAT * (NT_NEWS + 1) * CW);
  float* T1N = W + nxt((size_t)NGAT * 8 * CW);
  float* T02N = W + nxt((size_t)NGAT * 8 * CW);
  int* rlistN = (int*)(W + nxt((size_t)NGAT * NROW));
  float* rs1N = W + nxt((size_t)NGAT * NROW);
  int* boffN = (int*)(W + nxt((size_t)NGAT * (NB_NEWS + 2)));
  float* cand_enc = W + nxt((size_t)BN_B * NC * DD);
  float* clicked_enc = W + nxt((size_t)BN_B * NH * DD);
  float* WhU = W + nxt((size_t)NUSR * DD);
  float* s1u = W + nxt(NUSR);
  float* s2u = W + nxt(NUSR);
  __hip_bfloat16* BpN = (__hip_bfloat16*)(W + nxt((size_t)BPELT * 8 / 2));
  __hip_bfloat16* BpU = (__hip_bfloat16*)(W + nxt((size_t)BPELT * 8 / 2));
  __hip_bfloat16* WhiN = (__hip_bfloat16*)(W + nxt((size_t)WPELT * 8 / 2));
  __hip_bfloat16* WloN = (__hip_bfloat16*)(W + nxt((size_t)WPELT * 8 / 2));
  __hip_bfloat16* WhiU = (__hip_bfloat16*)(W + nxt((size_t)WPELT * 8 / 2));
  __hip_bfloat16* WloU = (__hip_bfloat16*)(W + nxt((size_t)WPELT * 8 / 2));
  __hip_bfloat16* Pm = (__hip_bfloat16*)(W + nxt((size_t)NUSR * PSTR / 2));
  __hip_bfloat16* BpP = (__hip_bfloat16*)(W + nxt((size_t)PPELT * 8 / 2));
  __hip_bfloat16* g_news = (__hip_bfloat16*)(W + nxt((size_t)NGAT * NROW * GSTR / 2));
  __hip_bfloat16* g_user = (__hip_bfloat16*)(W + nxt((size_t)NUSR * GSTR / 2));

  const int packgrid = (BPELT + 255) / 256;
  const int packWgrid = (WPELT + 255) / 256;

  // 1. packs
  k_packW<<<dim3(packWgrid, 2), 256, 0, stream>>>(news_W, user_W, WhiN, WloN, WhiU, WloU);
  k_packB<<<dim3(packgrid, 2), 256, 0, stream>>>(news_lw, user_lw, BpN, BpU);
  // 2. EW = emb @ news_W (LDS-staged split-bf16 MFMA) + fused s1/s2
  k_gemm_mfma<<<(NVOC + 127) / 128, 512, 0, stream>>>(emb, WhiN, WloN, news_a,
                                                      EW, s1v, s2v, NVOC);
  // 3. sort + exp tables + rank/bucket per news GAT
  k_sort2<<<NGAT, 1024, 0, stream>>>(cand, clicked, s2v, s1v, perm, E1, E02,
                                     rlistN, rs1N, boffN, NROW, NB_NEWS);
  // 4. coarse weighted prefix sums (local) + totals
  k_scan<<<dim3(8, NGAT), 320, 0, stream>>>(EW, perm, E1, E02, C1, C02, T1N, T02N,
                                            NROW, NT_NEWS + 1, 8);
  // 5. bucketed GAT rows (inline fix-up) -> g_news
  k_rows2<<<dim3(NB_NEWS + 1, NGAT), 320, 0, stream>>>(EW, perm, E1, E02, C1, C02, T1N, T02N,
                                                       rlistN, rs1N, boffN, g_news,
                                                       NROW, NT_NEWS, NROW, NB_NEWS, 8);
  // 6. fused news logits+attention -> cand/clicked encodings
  k_logits_attn<<<NGAT * NROW / 128, 512, 0, stream>>>(g_news, BpN, news_lb, news_q,
                                                       cand_enc, clicked_enc);
  // 7. user GEMM (+s1u/s2u)
  k_gemm_mfma<<<(NUSR + 127) / 128, 512, 0, stream>>>(clicked_enc, WhiU, WloU, user_a,
                                                      WhU, s1u, s2u, NUSR);
  // 8. user direct-P attention: build P, pack Wh_aug, P@Wh_aug -> g_user
  k_packP<<<(PPELT + 255) / 256, 256, 0, stream>>>(WhU, BpP);
  k_pbuild<<<(NUSR * PJT + 255) / 256, 256, 0, stream>>>(s1u, s2u, Pm);
  k_pgemm<<<NUSR / 64, 256, 0, stream>>>(Pm, BpP, g_user);
  // 9. fused user logits + attention + click score
  k_user_attn<<<BN_B, 256, 0, stream>>>(g_user, BpU, user_lb, user_q, cand_enc, out);
}

// Round 11
// 622.861 us; speedup vs baseline: 1.3928x; 1.3928x over previous
//
#include <hip/hip_runtime.h>
#include <hip/hip_bf16.h>

// Problem constants
#define BN_B 64
#define NC 5
#define NH 50
#define NL 32
#define DD 300
#define QQ 200
#define NVOC 50000
#define NGAT 55          // 5 candidate + 50 clicked news GATs
#define NROW 2048        // rows per news GAT (B*L)
#define NUSR 3200        // rows user GAT (B*H)
#define CW 304           // prefix array row width (300 data + col300 = denominator)
#define NT_NEWS 128      // 2048/16
#define NB_NEWS 128      // max bucket index = NROW/16
#define GSTR 320         // padded g row stride (10 K-tiles of 32 for MFMA)
#define NTILES_N 13      // ceil(200/16)
#define KTILES 10        // 320/32
#define BPELT (NTILES_N * KTILES * 64)  // lin_w B-fragment entries (x8 bf16)
#define WNT 19
#define WKT 10
#define WPELT (WNT * WKT * 64)
#define KTBYTES (NTILES_N * 64 * 16)    // bytes per kt lin_w B-tile = 13312
#define KTCHUNK (KTBYTES / 16)          // 832 16-B chunks
#define GCH 1216         // float4 chunks per kt per W matrix (WNT*64)
#define GKCH 2432        // hi+lo chunks per kt
// user direct-P GEMM: K = 3328 = 104 kts, N = 304 = 19 nts
#define PKT 104
#define PNT 19
#define PPELT (PKT * PNT * 64)
#define PSTR 3328
#define PJT 416          // 3328/8 j-groups per row
#define KSPLIT 8
#define KTPB 13          // PKT / KSPLIT

typedef short bf16x8 __attribute__((ext_vector_type(8)));
typedef short bf16x4 __attribute__((ext_vector_type(4)));
typedef float f32x4 __attribute__((ext_vector_type(4)));

static __device__ __forceinline__ float bf2f(short s) {
  return __uint_as_float(((unsigned)(unsigned short)s) << 16);
}

// ---------------------------------------------------------------------------
// Pack W [300,300] fp32 -> split bf16 (hi/lo) B-fragments. y = 0 news, 1 user.
// kt-major: entry e = (kt*WNT + nt)*64 + lane.
// ---------------------------------------------------------------------------
__global__ __launch_bounds__(256) void k_packW(const float* __restrict__ W0,
                                               const float* __restrict__ W1,
                                               __hip_bfloat16* __restrict__ h0,
                                               __hip_bfloat16* __restrict__ l0,
                                               __hip_bfloat16* __restrict__ h1,
                                               __hip_bfloat16* __restrict__ l1) {
  const float* Wm = blockIdx.y ? W1 : W0;
  __hip_bfloat16* Bhi = blockIdx.y ? h1 : h0;
  __hip_bfloat16* Blo = blockIdx.y ? l1 : l0;
  int e = blockIdx.x * 256 + threadIdx.x;
  if (e >= WPELT) return;
  int lane = e & 63, nt = (e >> 6) % WNT, kt = (e >> 6) / WNT;
  int n = nt * 16 + (lane & 15);
  int k0 = kt * 32 + (lane >> 4) * 8;
  __hip_bfloat16 hv[8], lv[8];
#pragma unroll
  for (int j = 0; j < 8; ++j) {
    int k = k0 + j;
    float v = (k < DD && n < DD) ? Wm[(size_t)k * DD + n] : 0.f;
    __hip_bfloat16 h = __float2bfloat16(v);
    hv[j] = h;
    lv[j] = __float2bfloat16(v - __bfloat162float(h));
  }
  *(bf16x8*)(Bhi + (size_t)e * 8) = *(const bf16x8*)hv;
  *(bf16x8*)(Blo + (size_t)e * 8) = *(const bf16x8*)lv;
}

// Pack lin_w [Q,300] -> bf16 B-fragments, kt-major. y = 0 news, 1 user.
__global__ __launch_bounds__(256) void k_packB(const float* __restrict__ lw0,
                                               const float* __restrict__ lw1,
                                               __hip_bfloat16* __restrict__ B0,
                                               __hip_bfloat16* __restrict__ B1) {
  const float* lw = blockIdx.y ? lw1 : lw0;
  __hip_bfloat16* Bp = blockIdx.y ? B1 : B0;
  int e = blockIdx.x * 256 + threadIdx.x;
  if (e >= BPELT) return;
  int lane = e & 63, nt = (e >> 6) % NTILES_N, kt = (e >> 6) / NTILES_N;
  int n = nt * 16 + (lane & 15);
  int k0 = kt * 32 + (lane >> 4) * 8;
  __hip_bfloat16 vals[8];
#pragma unroll
  for (int j = 0; j < 8; ++j) {
    int k = k0 + j;
    float v = (n < QQ && k < DD) ? lw[(size_t)n * DD + k] : 0.f;
    vals[j] = __float2bfloat16(v);
  }
  *(bf16x8*)(Bp + (size_t)e * 8) = *(const bf16x8*)vals;
}

// ---------------------------------------------------------------------------
// C[M,300] = A[M,300] @ W[300,300] via split-bf16 MFMA, LDS-STAGED B.
// Block = 512 threads (8 waves) = 128 rows. Fused s1/s2 epilogue.
// ---------------------------------------------------------------------------
__global__ __launch_bounds__(512) void k_gemm_mfma(const float* __restrict__ A,
                                                   const __hip_bfloat16* __restrict__ Bhi,
                                                   const __hip_bfloat16* __restrict__ Blo,
                                                   const float* __restrict__ avec,
                                                   float* __restrict__ C,
                                                   float* __restrict__ s1o,
                                                   float* __restrict__ s2o, int M) {
  __shared__ __align__(16) float4 Bs4[2][GKCH];
  const int tid = threadIdx.x;
  const int wave = tid >> 6, lane = tid & 63;
  const int quad = lane >> 4, l16 = lane & 15;
  const int rowA = blockIdx.x * 128 + wave * 16 + l16;
  const float* ar = A + (size_t)rowA * DD;
  const float4* hsrc = (const float4*)Bhi;
  const float4* lsrc = (const float4*)Blo;
  float4 st[5];

#define LOADKT(kt)                                                         \
  {                                                                        \
    _Pragma("unroll") for (int s = 0; s < 5; ++s) {                        \
      int idx = s * 512 + tid;                                             \
      if (idx < GKCH)                                                      \
        st[s] = (idx < GCH) ? hsrc[(size_t)(kt)*GCH + idx]                 \
                            : lsrc[(size_t)(kt)*GCH + idx - GCH];          \
    }                                                                      \
  }
#define STOREBUF(b)                                                        \
  {                                                                        \
    _Pragma("unroll") for (int s = 0; s < 5; ++s) {                        \
      int idx = s * 512 + tid;                                             \
      if (idx < GKCH) Bs4[b][idx] = st[s];                                 \
    }                                                                      \
  }

  LOADKT(0); STOREBUF(0); LOADKT(1);
  __syncthreads();

  f32x4 acc[WNT];
#pragma unroll
  for (int nt = 0; nt < WNT; ++nt) acc[nt] = (f32x4){0.f, 0.f, 0.f, 0.f};
  int c = 0;
  for (int kt = 0; kt < WKT; ++kt) {
    const int k0 = kt * 32 + quad * 8;
    float av[8];
    if (rowA < M && k0 + 8 <= DD) {
      float4 v0 = *(const float4*)(ar + k0);
      float4 v1 = *(const float4*)(ar + k0 + 4);
      av[0] = v0.x; av[1] = v0.y; av[2] = v0.z; av[3] = v0.w;
      av[4] = v1.x; av[5] = v1.y; av[6] = v1.z; av[7] = v1.w;
    } else {
#pragma unroll
      for (int j = 0; j < 8; ++j) {
        int k = k0 + j;
        av[j] = (rowA < M && k < DD) ? ar[k] : 0.f;
      }
    }
    __hip_bfloat16 hv[8], lv[8];
#pragma unroll
    for (int j = 0; j < 8; ++j) {
      __hip_bfloat16 h = __float2bfloat16(av[j]);
      hv[j] = h;
      lv[j] = __float2bfloat16(av[j] - __bfloat162float(h));
    }
    const bf16x8 ah = *(const bf16x8*)hv;
    const bf16x8 al = *(const bf16x8*)lv;
    const bf16x8* bh = (const bf16x8*)&Bs4[c][0] + lane;
    const bf16x8* bl = (const bf16x8*)&Bs4[c][GCH] + lane;
#pragma unroll
    for (int nt = 0; nt < WNT; ++nt) {
      bf16x8 bhf = bh[nt * 64], blf = bl[nt * 64];
      acc[nt] = __builtin_amdgcn_mfma_f32_16x16x32_bf16(ah, bhf, acc[nt], 0, 0, 0);
      acc[nt] = __builtin_amdgcn_mfma_f32_16x16x32_bf16(al, bhf, acc[nt], 0, 0, 0);
      acc[nt] = __builtin_amdgcn_mfma_f32_16x16x32_bf16(ah, blf, acc[nt], 0, 0, 0);
    }
    if (kt < WKT - 1) {
      __syncthreads();
      STOREBUF(c ^ 1);
      if (kt < WKT - 2) LOADKT(kt + 2);
      __syncthreads();
      c ^= 1;
    }
  }
  const int mbase = blockIdx.x * 128 + wave * 16 + quad * 4;
#pragma unroll
  for (int nt = 0; nt < WNT; ++nt) {
    int n = nt * 16 + l16;
    if (n < DD) {
#pragma unroll
      for (int r = 0; r < 4; ++r) {
        int mr = mbase + r;
        if (mr < M) C[(size_t)mr * DD + n] = acc[nt][r];
      }
    }
  }
  // s1/s2 epilogue
  float a1v[WNT], a2v[WNT];
#pragma unroll
  for (int nt = 0; nt < WNT; ++nt) {
    int n = nt * 16 + l16;
    a1v[nt] = (n < DD) ? avec[n] : 0.f;
    a2v[nt] = (n < DD) ? avec[DD + n] : 0.f;
  }
#pragma unroll
  for (int r = 0; r < 4; ++r) {
    float p1 = 0.f, p2 = 0.f;
#pragma unroll
    for (int nt = 0; nt < WNT; ++nt) {
      p1 = fmaf(acc[nt][r], a1v[nt], p1);
      p2 = fmaf(acc[nt][r], a2v[nt], p2);
    }
    p1 += __shfl_xor(p1, 1, 64); p1 += __shfl_xor(p1, 2, 64);
    p1 += __shfl_xor(p1, 4, 64); p1 += __shfl_xor(p1, 8, 64);
    p2 += __shfl_xor(p2, 1, 64); p2 += __shfl_xor(p2, 2, 64);
    p2 += __shfl_xor(p2, 4, 64); p2 += __shfl_xor(p2, 8, 64);
    int mr = mbase + r;
    if (l16 == 0 && mr < M) { s1o[mr] = p1; s2o[mr] = p2; }
  }
#undef LOADKT
#undef STOREBUF
}

// ---------------------------------------------------------------------------
// Bitonic sort of s2 + exp tables + rank/bucket epilogue (news GATs).
// ---------------------------------------------------------------------------
__global__ __launch_bounds__(1024) void k_sort2(const int* __restrict__ cand,
                                                const int* __restrict__ clicked,
                                                const float* __restrict__ s2src,
                                                const float* __restrict__ s1src,
                                                int* __restrict__ perm,
                                                float* __restrict__ E1, float* __restrict__ E02,
                                                int* __restrict__ rlist, float* __restrict__ rs1,
                                                int* __restrict__ boff,
                                                int N, int NB) {
  __shared__ float sval[2048];
  __shared__ int spay[2048];
  __shared__ int cnt[224];
  __shared__ int ofs[224];
  const int m = blockIdx.x;
  const int tid = threadIdx.x;
  int* perm_g = perm + (size_t)m * N;
  float* E1_g = E1 + (size_t)m * N;
  float* E02_g = E02 + (size_t)m * N;

  for (int i = tid; i < N; i += 1024) {
    int b = i >> 5, l = i & 31;
    int tok = (m < NC) ? cand[b * (NC * NL) + m * NL + l]
                       : clicked[b * (NH * NL) + (m - NC) * NL + l];
    sval[i] = s2src[tok]; spay[i] = tok;
  }
  __syncthreads();
  for (int k = 2; k <= N; k <<= 1) {
    for (int j = k >> 1; j > 0; j >>= 1) {
      for (int i = tid; i < N; i += 1024) {
        int ixj = i ^ j;
        if (ixj > i) {
          bool asc = ((i & k) == 0);
          float a = sval[i], bb = sval[ixj];
          bool sw = asc ? (a > bb) : (a < bb);
          if (sw) {
            sval[i] = bb; sval[ixj] = a;
            int t = spay[i]; spay[i] = spay[ixj]; spay[ixj] = t;
          }
        }
      }
      __syncthreads();
    }
  }
  for (int i = tid; i < N; i += 1024) {
    E1_g[i] = expf(sval[i]);
    E02_g[i] = expf(0.2f * sval[i]);
    perm_g[i] = spay[i];
  }
  __syncthreads();
  for (int t = tid; t <= NB; t += 1024) cnt[t] = 0;
  __syncthreads();
  int* kil = spay;  // reuse (perm already written)
  for (int r = tid; r < N; r += 1024) {
    int b = r >> 5, l = r & 31;
    int tok = (m < NC) ? cand[b * (NC * NL) + m * NL + l]
                       : clicked[b * (NH * NL) + (m - NC) * NL + l];
    float tau = -s1src[tok];
    int lo = 0, hi = N;
    while (lo < hi) { int mid = (lo + hi) >> 1; if (sval[mid] <= tau) lo = mid + 1; else hi = mid; }
    kil[r] = lo;
    atomicAdd(&cnt[lo >> 4], 1);
  }
  __syncthreads();
  if (tid == 0) {
    int run = 0;
    for (int t = 0; t <= NB; ++t) { ofs[t] = run; run += cnt[t]; cnt[t] = ofs[t]; }
  }
  __syncthreads();
  int* rlist_g = rlist + (size_t)m * N;
  float* rs1_g = rs1 + (size_t)m * N;
  for (int r = tid; r < N; r += 1024) {
    int ki = kil[r];
    int pos = atomicAdd(&cnt[ki >> 4], 1);
    rlist_g[pos] = (ki << 16) | r;
    int b = r >> 5, l = r & 31;
    int tok = (m < NC) ? cand[b * (NC * NL) + m * NL + l]
                       : clicked[b * (NH * NL) + (m - NC) * NL + l];
    rs1_g[pos] = s1src[tok];
  }
  int* boff_g = boff + (size_t)m * (NB + 2);
  for (int t = tid; t <= NB; t += 1024) boff_g[t] = ofs[t];
  if (tid == 0) boff_g[NB + 1] = N;
}

// ---------------------------------------------------------------------------
// Chunked weighted prefix accumulation (local prefixes) + chunk totals T.
// ---------------------------------------------------------------------------
__global__ __launch_bounds__(320) void k_scan(const float* __restrict__ base,
                                              const int* __restrict__ perm,
                                              const float* __restrict__ E1,
                                              const float* __restrict__ E02,
                                              float* __restrict__ C1, float* __restrict__ C02,
                                              float* __restrict__ T1, float* __restrict__ T02,
                                              int Epad, int cstride, int nkc) {
  const int g = blockIdx.y, kc = blockIdx.x;
  const int col = threadIdx.x;
  const int* perm_g = perm + (size_t)g * Epad;
  const float* E1_g = E1 + (size_t)g * Epad;
  const float* E02_g = E02 + (size_t)g * Epad;
  float* C1_g = C1 + (size_t)g * cstride * CW;
  float* C02_g = C02 + (size_t)g * cstride * CW;
  const bool datacol = (col < DD);
  const float wden = (col == DD) ? 1.f : 0.f;
  float acc1 = 0.f, acc2 = 0.f;
  const int k0 = kc * 256;
#pragma unroll 8
  for (int kk = 0; kk < 256; ++kk) {
    int k = k0 + kk;
    int tok = perm_g[k];
    float e1 = E1_g[k], e02 = E02_g[k];
    float w = datacol ? base[(size_t)tok * DD + col] : wden;
    acc1 = fmaf(e1, w, acc1);
    acc2 = fmaf(e02, w, acc2);
    if ((kk & 15) == 15) {
      int t = (k + 1) >> 4;
      if (col < CW) { C1_g[(size_t)t * CW + col] = acc1; C02_g[(size_t)t * CW + col] = acc2; }
    }
  }
  if (col < CW) {
    T1[((size_t)g * nkc + kc) * CW + col] = acc1;
    T02[((size_t)g * nkc + kc) * CW + col] = acc2;
  }
}

// ---------------------------------------------------------------------------
// Bucketed GAT row construction with inline prefix fix-up (news path).
// ---------------------------------------------------------------------------
__global__ __launch_bounds__(320) void k_rows2(
    const float* __restrict__ base,
    const int* __restrict__ perm, const float* __restrict__ E1, const float* __restrict__ E02,
    const float* __restrict__ C1, const float* __restrict__ C02,
    const float* __restrict__ T1, const float* __restrict__ T02,
    const int* __restrict__ rlist, const float* __restrict__ rs1,
    const int* __restrict__ boff,
    __hip_bfloat16* __restrict__ gout,
    int N, int NT, int Epad, int NB, int nkc) {
  __shared__ float U1[16][CW];
  __shared__ float U02[16][CW];
  __shared__ int tokL[16];
  __shared__ float e1L[16], e02L[16];
  const int t = blockIdx.x, g = blockIdx.y;
  const int col = threadIdx.x;
  const int* boff_g = boff + (size_t)g * (NB + 2);
  const int i0 = boff_g[t], i1 = boff_g[t + 1];
  if (i0 >= i1) return;
  const int* perm_g = perm + (size_t)g * Epad;
  const float* E1_g = E1 + (size_t)g * Epad;
  const float* E02_g = E02 + (size_t)g * Epad;
  if (col < 16) {
    int idx = t * 16 + col;
    bool v = idx < N;
    tokL[col] = v ? perm_g[idx] : 0;
    e1L[col] = v ? E1_g[idx] : 0.f;
    e02L[col] = v ? E02_g[idx] : 0.f;
  }
  __syncthreads();
  if (col < CW) {
    const int kc = (t == 0) ? 0 : ((t - 1) >> 4);
    float tot1 = 0.f, pre1 = 0.f, pre02 = 0.f;
#pragma unroll
    for (int c = 0; c < 13; ++c) {
      if (c < nkc) {
        float tv = T1[((size_t)g * nkc + c) * CW + col];
        tot1 += tv;
        if (c < kc) {
          pre1 += tv;
          pre02 += T02[((size_t)g * nkc + c) * CW + col];
        }
      }
    }
    if (t > 0) {
      pre1 += C1[((size_t)g * (NT + 1) + t) * CW + col];
      pre02 += C02[((size_t)g * (NT + 1) + t) * CW + col];
    }
    float u1 = tot1 - pre1;
    float u02 = pre02;
    float wv[16];
#pragma unroll
    for (int j = 0; j < 16; ++j) {
      if (col < DD) wv[j] = ((t * 16 + j) < N) ? base[(size_t)tokL[j] * DD + col] : 0.f;
      else wv[j] = (col == DD) ? 1.f : 0.f;
    }
#pragma unroll
    for (int j = 0; j < 16; ++j) {
      U1[j][col] = u1; U02[j][col] = u02;
      u1 = fmaf(-e1L[j], wv[j], u1);
      u02 = fmaf(e02L[j], wv[j], u02);
    }
  }
  __syncthreads();
  const int wave = col >> 6, lane = col & 63;
  const int* rlist_g = rlist + (size_t)g * N;
  const float* rs1_g = rs1 + (size_t)g * N;
  for (int i = i0 + wave; i < i1; i += 5) {
    int e = rlist_g[i];
    int r = e & 0xffff, nr = (e >> 16) & 15;
    float s1 = rs1_g[i];
    float es1 = __expf(s1), es02 = __expf(0.2f * s1);
    float den = es1 * U1[nr][DD] + es02 * U02[nr][DD];
    float rden = 1.f / den;
    __hip_bfloat16* gr = gout + ((size_t)g * N + r) * GSTR;
#pragma unroll
    for (int cc = 0; cc < 2; ++cc) {
      int ch = lane + 64 * cc;               // 16-B column chunk index
      if (ch < 80) {
        short ov[4];
        if (ch < 75) {                        // cols 0..299
          const int c0 = ch * 4;
          float4 u1v = *(const float4*)&U1[nr][c0];
          float4 u2v = *(const float4*)&U02[nr][c0];
          float n0 = fmaf(es1, u1v.x, es02 * u2v.x) * rden;
          float n1 = fmaf(es1, u1v.y, es02 * u2v.y) * rden;
          float n2 = fmaf(es1, u1v.z, es02 * u2v.z) * rden;
          float n3 = fmaf(es1, u1v.w, es02 * u2v.w) * rden;
          float g0 = (n0 > 0.f) ? n0 : (__expf(n0) - 1.f);
          float g1 = (n1 > 0.f) ? n1 : (__expf(n1) - 1.f);
          float g2 = (n2 > 0.f) ? n2 : (__expf(n2) - 1.f);
          float g3 = (n3 > 0.f) ? n3 : (__expf(n3) - 1.f);
          __hip_bfloat16 h0 = __float2bfloat16(g0), h1 = __float2bfloat16(g1);
          __hip_bfloat16 h2 = __float2bfloat16(g2), h3 = __float2bfloat16(g3);
          ov[0] = *(short*)&h0; ov[1] = *(short*)&h1;
          ov[2] = *(short*)&h2; ov[3] = *(short*)&h3;
        } else {                              // cols 300..319 zero pad
          ov[0] = ov[1] = ov[2] = ov[3] = 0;
        }
        *(bf16x4*)(gr + ch * 4) = *(bf16x4*)ov;
      }
    }
  }
}

// ---------------------------------------------------------------------------
// Fused news logits + additive attention, LDS-staged B. 512 thr = 128 rows.
// ---------------------------------------------------------------------------
__global__ __launch_bounds__(512) void k_logits_attn(
    const __hip_bfloat16* __restrict__ g, const __hip_bfloat16* __restrict__ Bp,
    const float* __restrict__ lin_b, const float* __restrict__ query,
    float* __restrict__ cand_enc, float* __restrict__ clicked_enc) {
  __shared__ __align__(16) short Bs[2][NTILES_N * 512];  // 2 x 13312 B
  __shared__ float lg[128];
  __shared__ float wgt[128];
  __shared__ float accw[8][GSTR];
  const int tid = threadIdx.x;
  const int wave = tid >> 6, lane = tid & 63;
  const int quad = lane >> 4, l16 = lane & 15;
  const int m = blockIdx.x >> 4;             // 16 blocks per gat
  const int rbase = (blockIdx.x & 15) * 128; // row within gat
  const __hip_bfloat16* grow =
      g + ((size_t)m * NROW + rbase + wave * 16 + l16) * GSTR + quad * 8;
  bf16x8 afr[KTILES];
#pragma unroll
  for (int kt = 0; kt < KTILES; ++kt) afr[kt] = *(const bf16x8*)(grow + kt * 32);

  const float4* bsrc = (const float4*)Bp;
  float4* bdst0 = (float4*)&Bs[0][0];
  float4* bdst1 = (float4*)&Bs[1][0];
  float4 st0, st1;
  {
    st0 = bsrc[tid];
    if (tid < KTCHUNK - 512) st1 = bsrc[512 + tid];
    bdst0[tid] = st0;
    if (tid < KTCHUNK - 512) bdst0[512 + tid] = st1;
    st0 = bsrc[KTCHUNK + tid];
    if (tid < KTCHUNK - 512) st1 = bsrc[KTCHUNK + 512 + tid];
  }
  __syncthreads();
  f32x4 acc[NTILES_N];
#pragma unroll
  for (int nt = 0; nt < NTILES_N; ++nt) acc[nt] = (f32x4){0.f, 0.f, 0.f, 0.f};
  int c = 0;
  for (int kt = 0; kt < KTILES; ++kt) {
    const bf16x8* bp = (const bf16x8*)&Bs[c][0] + lane;
#pragma unroll
    for (int nt = 0; nt < NTILES_N; ++nt)
      acc[nt] = __builtin_amdgcn_mfma_f32_16x16x32_bf16(afr[kt], bp[nt * 64], acc[nt], 0, 0, 0);
    if (kt < KTILES - 1) {
      __syncthreads();
      float4* bd = c ? bdst0 : bdst1;
      bd[tid] = st0;
      if (tid < KTCHUNK - 512) bd[512 + tid] = st1;
      if (kt < KTILES - 2) {
        st0 = bsrc[(size_t)(kt + 2) * KTCHUNK + tid];
        if (tid < KTCHUNK - 512) st1 = bsrc[(size_t)(kt + 2) * KTCHUNK + 512 + tid];
      }
      __syncthreads();
      c ^= 1;
    }
  }
  float part[4] = {0.f, 0.f, 0.f, 0.f};
#pragma unroll
  for (int nt = 0; nt < NTILES_N; ++nt) {
    const int n = nt * 16 + l16;
    const float qv = (n < QQ) ? query[n] : 0.f;
    const float bv = (n < QQ) ? lin_b[n] : 0.f;
#pragma unroll
    for (int r = 0; r < 4; ++r)
      part[r] = fmaf(tanhf(acc[nt][r] + bv), qv, part[r]);
  }
#pragma unroll
  for (int r = 0; r < 4; ++r) {
    float p = part[r];
    p += __shfl_xor(p, 1, 64); p += __shfl_xor(p, 2, 64);
    p += __shfl_xor(p, 4, 64); p += __shfl_xor(p, 8, 64);
    if (l16 == 0) lg[wave * 16 + quad * 4 + r] = p;
  }
  __syncthreads();
  if (tid < 128) {
    float v = lg[tid];
    float mx = v;
    mx = fmaxf(mx, __shfl_xor(mx, 1, 64)); mx = fmaxf(mx, __shfl_xor(mx, 2, 64));
    mx = fmaxf(mx, __shfl_xor(mx, 4, 64)); mx = fmaxf(mx, __shfl_xor(mx, 8, 64));
    mx = fmaxf(mx, __shfl_xor(mx, 16, 64));
    float e = expf(v - mx), sm = e;
    sm += __shfl_xor(sm, 1, 64); sm += __shfl_xor(sm, 2, 64);
    sm += __shfl_xor(sm, 4, 64); sm += __shfl_xor(sm, 8, 64);
    sm += __shfl_xor(sm, 16, 64);
    wgt[tid] = e / sm;
  }
  __syncthreads();
  const float w = wgt[wave * 16 + l16];
#pragma unroll
  for (int kt = 0; kt < KTILES; ++kt) {
#pragma unroll
    for (int j = 0; j < 8; ++j) {
      float v = bf2f(afr[kt][j]) * w;
      v += __shfl_xor(v, 1, 64); v += __shfl_xor(v, 2, 64);
      v += __shfl_xor(v, 4, 64); v += __shfl_xor(v, 8, 64);
      if (l16 == 0) accw[wave][kt * 32 + quad * 8 + j] = v;
    }
  }
  __syncthreads();
  const int b0 = rbase >> 5;
  for (int idx = tid; idx < 4 * DD; idx += 512) {
    int j = idx / DD, cc = idx % DD;
    float* op = (m < NC) ? (cand_enc + ((size_t)(b0 + j) * NC + m) * DD)
                         : (clicked_enc + ((size_t)(b0 + j) * NH + (m - NC)) * DD);
    op[cc] = accw[2 * j][cc] + accw[2 * j + 1][cc];
  }
}

// ---------------------------------------------------------------------------
// USER PATH (direct rank-1 attention, split-K for occupancy):
// P[i,j] = exp(leaky(s1_i + s2_j)) bf16; g_user = elu((P@Wh_aug)/den).
// ---------------------------------------------------------------------------
// Build P [NUSR x PSTR] bf16.
__global__ __launch_bounds__(256) void k_pbuild(const float* __restrict__ s1u,
                                                const float* __restrict__ s2u,
                                                __hip_bfloat16* __restrict__ P) {
  int gid = blockIdx.x * 256 + threadIdx.x;
  if (gid >= NUSR * PJT) return;
  int i = gid / PJT, jg = gid % PJT;
  int j0 = jg * 8;
  float s1 = s1u[i];
  __hip_bfloat16 ov[8];
#pragma unroll
  for (int q = 0; q < 8; ++q) {
    int j = j0 + q;
    float w = 0.f;
    if (j < NUSR) {
      float s = s1 + s2u[j];
      w = __expf(s > 0.f ? s : 0.2f * s);
    }
    ov[q] = __float2bfloat16(w);
  }
  *(bf16x8*)(P + (size_t)i * PSTR + j0) = *(const bf16x8*)ov;
}

// Pack Wh_aug [K=3328 x N=304] -> bf16 B-fragments, kt-major. col 300 = ones.
__global__ __launch_bounds__(256) void k_packP(const float* __restrict__ Wh,
                                               __hip_bfloat16* __restrict__ Bp) {
  int e = blockIdx.x * 256 + threadIdx.x;
  if (e >= PPELT) return;
  int lane = e & 63, nt = (e >> 6) % PNT, kt = (e >> 6) / PNT;
  int n = nt * 16 + (lane & 15);
  int k0 = kt * 32 + (lane >> 4) * 8;
  __hip_bfloat16 vals[8];
#pragma unroll
  for (int j = 0; j < 8; ++j) {
    int k = k0 + j;
    float v = 0.f;
    if (k < NUSR) {
      if (n < DD) v = Wh[(size_t)k * DD + n];
      else if (n == DD) v = 1.f;
    }
    vals[j] = __float2bfloat16(v);
  }
  *(bf16x8*)(Bp + (size_t)e * 8) = *(const bf16x8*)vals;
}

// Split-K partial GEMM: grid (NUSR/64, KSPLIT). No LDS, no barriers; 19
// independent accumulators; B-frags stream from L2 (pack = 2 MB, resident).
__global__ __launch_bounds__(256) void k_pgemm2(const __hip_bfloat16* __restrict__ P,
                                                const __hip_bfloat16* __restrict__ Bp,
                                                float* __restrict__ part) {
  const int tid = threadIdx.x;
  const int wave = tid >> 6, lane = tid & 63;
  const int quad = lane >> 4, l16 = lane & 15;
  const int rowA = blockIdx.x * 64 + wave * 16 + l16;
  const int ks = blockIdx.y;
  const __hip_bfloat16* ar = P + (size_t)rowA * PSTR + ks * KTPB * 32 + quad * 8;
  f32x4 acc[PNT];
#pragma unroll
  for (int nt = 0; nt < PNT; ++nt) acc[nt] = (f32x4){0.f, 0.f, 0.f, 0.f};
  for (int kk = 0; kk < KTPB; ++kk) {
    bf16x8 a = *(const bf16x8*)(ar + kk * 32);
    const bf16x8* bp = (const bf16x8*)Bp + (size_t)(ks * KTPB + kk) * PNT * 64 + lane;
#pragma unroll
    for (int nt = 0; nt < PNT; ++nt)
      acc[nt] = __builtin_amdgcn_mfma_f32_16x16x32_bf16(a, bp[nt * 64], acc[nt], 0, 0, 0);
  }
  float* pr = part + ((size_t)ks * NUSR + blockIdx.x * 64 + wave * 16 + quad * 4) * CW;
#pragma unroll
  for (int nt = 0; nt < PNT; ++nt) {
    int n = nt * 16 + l16;
#pragma unroll
    for (int r = 0; r < 4; ++r)
      pr[(size_t)r * CW + n] = acc[nt][r];
  }
}

// Reduce KSPLIT partials, normalize by col 300, elu, emit bf16 g_user row.
__global__ __launch_bounds__(320) void k_pfinal(const float* __restrict__ part,
                                                __hip_bfloat16* __restrict__ gout) {
  __shared__ float dsh;
  const int row = blockIdx.x, col = threadIdx.x;
  float s = 0.f;
  if (col < CW) {
#pragma unroll
    for (int ks = 0; ks < KSPLIT; ++ks)
      s += part[((size_t)ks * NUSR + row) * CW + col];
  }
  if (col == DD) dsh = s;
  __syncthreads();
  const float rden = 1.f / dsh;
  float v = 0.f;
  if (col < DD) {
    float x = s * rden;
    v = (x > 0.f) ? x : (__expf(x) - 1.f);
  }
  gout[(size_t)row * GSTR + col] = __float2bfloat16(v);
}

// ---------------------------------------------------------------------------
// Fused user logits + attention + click-score dot. Block = one b (50 rows).
// ---------------------------------------------------------------------------
__global__ __launch_bounds__(256) void k_user_attn(
    const __hip_bfloat16* __restrict__ g, const __hip_bfloat16* __restrict__ Bp,
    const float* __restrict__ lin_b, const float* __restrict__ query,
    const float* __restrict__ cand_enc, float* __restrict__ out) {
  __shared__ float lg[64];
  __shared__ float wgt[64];
  __shared__ float accw[4][GSTR];
  __shared__ float uenc[CW];
  __shared__ float wred[4];
  const int b = blockIdx.x, tid = threadIdx.x;
  const int wave = tid >> 6, lane = tid & 63;
  const int quad = lane >> 4, l16 = lane & 15;
  const int rl = wave * 16 + l16;
  const int rclamp = (rl < NH) ? rl : 0;
  const __hip_bfloat16* grow = g + ((size_t)b * NH + rclamp) * GSTR + quad * 8;
  bf16x8 afr[KTILES];
#pragma unroll
  for (int kt = 0; kt < KTILES; ++kt) afr[kt] = *(const bf16x8*)(grow + kt * 32);
  f32x4 acc[NTILES_N];
#pragma unroll
  for (int nt = 0; nt < NTILES_N; ++nt) acc[nt] = (f32x4){0.f, 0.f, 0.f, 0.f};
  for (int kt = 0; kt < KTILES; ++kt) {
    const bf16x8* bp = (const bf16x8*)Bp + (size_t)kt * NTILES_N * 64 + lane;
#pragma unroll
    for (int nt = 0; nt < NTILES_N; ++nt)
      acc[nt] = __builtin_amdgcn_mfma_f32_16x16x32_bf16(afr[kt], bp[nt * 64], acc[nt], 0, 0, 0);
  }
  float part[4] = {0.f, 0.f, 0.f, 0.f};
#pragma unroll
  for (int nt = 0; nt < NTILES_N; ++nt) {
    const int n = nt * 16 + l16;
    const float qv = (n < QQ) ? query[n] : 0.f;
    const float bv = (n < QQ) ? lin_b[n] : 0.f;
#pragma unroll
    for (int r = 0; r < 4; ++r)
      part[r] = fmaf(tanhf(acc[nt][r] + bv), qv, part[r]);
  }
#pragma unroll
  for (int r = 0; r < 4; ++r) {
    float p = part[r];
    p += __shfl_xor(p, 1, 64); p += __shfl_xor(p, 2, 64);
    p += __shfl_xor(p, 4, 64); p += __shfl_xor(p, 8, 64);
    if (l16 == 0) lg[wave * 16 + quad * 4 + r] = p;
  }
  __syncthreads();
  if (tid < 64) {
    float v = (tid < NH) ? lg[tid] : -3.4e38f;
    float mx = v;
    for (int o = 32; o; o >>= 1) mx = fmaxf(mx, __shfl_xor(mx, o, 64));
    float e = (tid < NH) ? expf(v - mx) : 0.f;
    float sm = e;
    for (int o = 32; o; o >>= 1) sm += __shfl_xor(sm, o, 64);
    wgt[tid] = (tid < NH) ? e / sm : 0.f;
  }
  __syncthreads();
  const float w = (rl < NH) ? wgt[rl] : 0.f;
#pragma unroll
  for (int kt = 0; kt < KTILES; ++kt) {
#pragma unroll
    for (int j = 0; j < 8; ++j) {
      float v = bf2f(afr[kt][j]) * w;
      v += __shfl_xor(v, 1, 64); v += __shfl_xor(v, 2, 64);
      v += __shfl_xor(v, 4, 64); v += __shfl_xor(v, 8, 64);
      if (l16 == 0) accw[wave][kt * 32 + quad * 8 + j] = v;
    }
  }
  __syncthreads();
  for (int c = tid; c < DD; c += 256)
    uenc[c] = accw[0][c] + accw[1][c] + accw[2][c] + accw[3][c];
  __syncthreads();
  for (int c5 = 0; c5 < NC; ++c5) {
    const float* cp = cand_enc + ((size_t)b * NC + c5) * DD;
    float s = 0.f;
    for (int d = tid; d < DD; d += 256) s = fmaf(uenc[d], cp[d], s);
    for (int o = 32; o; o >>= 1) s += __shfl_xor(s, o, 64);
    if (lane == 0) wred[wave] = s;
    __syncthreads();
    if (tid == 0) out[b * NC + c5] = wred[0] + wred[1] + wred[2] + wred[3];
    __syncthreads();
  }
}

// ---------------------------------------------------------------------------
extern "C" void kernel_launch(void* const* d_in, const int* in_sizes, int n_in,
                              void* d_out, int out_size, void* d_ws, size_t ws_size,
                              hipStream_t stream) {
  const int* cand = (const int*)d_in[0];
  const int* clicked = (const int*)d_in[1];
  const float* emb = (const float*)d_in[2];
  const float* news_W = (const float*)d_in[3];
  const float* news_a = (const float*)d_in[4];
  const float* news_lw = (const float*)d_in[5];
  const float* news_lb = (const float*)d_in[6];
  const float* news_q = (const float*)d_in[7];
  const float* user_W = (const float*)d_in[8];
  const float* user_a = (const float*)d_in[9];
  const float* user_lw = (const float*)d_in[10];
  const float* user_lb = (const float*)d_in[11];
  const float* user_q = (const float*)d_in[12];
  float* out = (float*)d_out;

  float* W = (float*)d_ws;
  size_t o = 0;
  auto nxt = [&](size_t n) { size_t c = o; o += (n + 63) & ~(size_t)63; return c; };
  float* EW = W + nxt((size_t)NVOC * DD);
  float* s1v = W + nxt(NVOC);
  float* s2v = W + nxt(NVOC);
  int* perm = (int*)(W + nxt((size_t)NGAT * NROW));
  float* E1 = W + nxt((size_t)NGAT * NROW);
  float* E02 = W + nxt((size_t)NGAT * NROW);
  float* C1 = W + nxt((size_t)NGAT * (NT_NEWS + 1) * CW);
  float* C02 = W + nxt((size_t)NGAT * (NT_NEWS + 1) * CW);
  float* T1N = W + nxt((size_t)NGAT * 8 * CW);
  float* T02N = W + nxt((size_t)NGAT * 8 * CW);
  int* rlistN = (int*)(W + nxt((size_t)NGAT * NROW));
  float* rs1N = W + nxt((size_t)NGAT * NROW);
  int* boffN = (int*)(W + nxt((size_t)NGAT * (NB_NEWS + 2)));
  float* cand_enc = W + nxt((size_t)BN_B * NC * DD);
  float* clicked_enc = W + nxt((size_t)BN_B * NH * DD);
  float* WhU = W + nxt((size_t)NUSR * DD);
  float* s1u = W + nxt(NUSR);
  float* s2u = W + nxt(NUSR);
  __hip_bfloat16* BpN = (__hip_bfloat16*)(W + nxt((size_t)BPELT * 8 / 2));
  __hip_bfloat16* BpU = (__hip_bfloat16*)(W + nxt((size_t)BPELT * 8 / 2));
  __hip_bfloat16* WhiN = (__hip_bfloat16*)(W + nxt((size_t)WPELT * 8 / 2));
  __hip_bfloat16* WloN = (__hip_bfloat16*)(W + nxt((size_t)WPELT * 8 / 2));
  __hip_bfloat16* WhiU = (__hip_bfloat16*)(W + nxt((size_t)WPELT * 8 / 2));
  __hip_bfloat16* WloU = (__hip_bfloat16*)(W + nxt((size_t)WPELT * 8 / 2));
  __hip_bfloat16* Pm = (__hip_bfloat16*)(W + nxt((size_t)NUSR * PSTR / 2));
  __hip_bfloat16* BpP = (__hip_bfloat16*)(W + nxt((size_t)PPELT * 8 / 2));
  __hip_bfloat16* g_news = (__hip_bfloat16*)(W + nxt((size_t)NGAT * NROW * GSTR / 2));
  __hip_bfloat16* g_user = (__hip_bfloat16*)(W + nxt((size_t)NUSR * GSTR / 2));
  // Split-K partials (KSPLIT*NUSR*CW fp32 = 31.1 MB) alias the EW buffer
  // (60.8 MB): EW's last reader is k_rows2 (news), which completes before
  // the user path runs. Same launch order every call -> graph-capture safe.
  float* partU = EW;

  const int packgrid = (BPELT + 255) / 256;
  const int packWgrid = (WPELT + 255) / 256;

  // 1. packs
  k_packW<<<dim3(packWgrid, 2), 256, 0, stream>>>(news_W, user_W, WhiN, WloN, WhiU, WloU);
  k_packB<<<dim3(packgrid, 2), 256, 0, stream>>>(news_lw, user_lw, BpN, BpU);
  // 2. EW = emb @ news_W (LDS-staged split-bf16 MFMA) + fused s1/s2
  k_gemm_mfma<<<(NVOC + 127) / 128, 512, 0, stream>>>(emb, WhiN, WloN, news_a,
                                                      EW, s1v, s2v, NVOC);
  // 3. sort + exp tables + rank/bucket per news GAT
  k_sort2<<<NGAT, 1024, 0, stream>>>(cand, clicked, s2v, s1v, perm, E1, E02,
                                     rlistN, rs1N, boffN, NROW, NB_NEWS);
  // 4. coarse weighted prefix sums (local) + totals
  k_scan<<<dim3(8, NGAT), 320, 0, stream>>>(EW, perm, E1, E02, C1, C02, T1N, T02N,
                                            NROW, NT_NEWS + 1, 8);
  // 5. bucketed GAT rows (inline fix-up) -> g_news
  k_rows2<<<dim3(NB_NEWS + 1, NGAT), 320, 0, stream>>>(EW, perm, E1, E02, C1, C02, T1N, T02N,
                                                       rlistN, rs1N, boffN, g_news,
                                                       NROW, NT_NEWS, NROW, NB_NEWS, 8);
  // 6. fused news logits+attention -> cand/clicked encodings
  k_logits_attn<<<NGAT * NROW / 128, 512, 0, stream>>>(g_news, BpN, news_lb, news_q,
                                                       cand_enc, clicked_enc);
  // 7. user GEMM (+s1u/s2u)
  k_gemm_mfma<<<(NUSR + 127) / 128, 512, 0, stream>>>(clicked_enc, WhiU, WloU, user_a,
                                                      WhU, s1u, s2u, NUSR);
  // 8. user direct-P attention (split-K): build P, pack Wh_aug,
  //    partial P@Wh_aug, reduce+normalize+elu -> g_user
  k_packP<<<(PPELT + 255) / 256, 256, 0, stream>>>(WhU, BpP);
  k_pbuild<<<(NUSR * PJT + 255) / 256, 256, 0, stream>>>(s1u, s2u, Pm);
  k_pgemm2<<<dim3(NUSR / 64, KSPLIT), 256, 0, stream>>>(Pm, BpP, partU);
  k_pfinal<<<NUSR, 320, 0, stream>>>(partU, g_user);
  // 9. fused user logits + attention + click score
  k_user_attn<<<BN_B, 256, 0, stream>>>(g_user, BpU, user_lb, user_q, cand_enc, out);
}